// Round 1
// baseline (18981.070 us; speedup 1.0000x reference)
//
#include <hip/hip_runtime.h>

#define Bv 32
#define Sv 256
#define Iv 256
#define Cv 512
#define Nv 1024
#define Vv 64
#define Ov 256
#define NBLK 256
#define NTHR 256

// ws layout (float indices)
#define HOFF    128                       // h[2][B][C]
#define RVOFF   (HOFF + 2*Bv*Cv)          // 32896: rv[B][V]
#define SUMOFF  (RVOFF + Bv*Vv)           // 34944: sums[B][8]
#define HEADOFF (SUMOFF + Bv*8)           // 35200: heads[260][B]
#define ZERO_BYTES (HEADOFF * 4)          // 140800 bytes zeroed per launch

struct KP {
  const float *x, *Wih, *Whh, *bih, *bhh;
  const float *rkW, *rkb, *rsW, *rsb, *rgW, *rgb, *rgammaW, *rgammab;
  const float *wkW, *wkb, *wsW, *wsb, *weW, *web, *waW, *wab;
  const float *outW, *outb;
  float *out;      // outs region of d_out
  float *memout;   // final-memory region of d_out
  float *ws;
};

__device__ inline float sigf(float x){ return 1.f/(1.f+expf(-x)); }
__device__ inline float softplusf(float x){ return fmaxf(x,0.f) + log1pf(expf(-fabsf(x))); }
__device__ inline float blo(unsigned u){ return __uint_as_float(u<<16); }
__device__ inline float bhi(unsigned u){ return __uint_as_float(u & 0xffff0000u); }
__device__ inline unsigned short f2bf(float f){
  unsigned u = __float_as_uint(f);
  return (unsigned short)((u + 0x7fffu + ((u>>16)&1u)) >> 16);
}
__device__ inline unsigned packbf(float a, float b){
  return (unsigned)f2bf(a) | ((unsigned)f2bf(b) << 16);
}

__device__ inline float headact(int o, float s){
  if (o < 64)  return tanhf(s);        // r_key
  if (o == 64) return softplusf(s);    // r_str
  if (o == 65) return sigf(s);         // r_gate
  if (o == 66) return 1.f + softplusf(s); // r_gamma
  if (o < 131) return tanhf(s);        // w_key
  if (o == 131) return softplusf(s);   // w_str
  if (o < 196) return sigf(s);         // w_erase
  return tanhf(s);                     // w_add
}

__device__ inline void head_src(const KP& P, int o, const float** row, float* bias){
  if (o < 64)       { *row = P.rkW + o*Cv;        *bias = P.rkb[o]; }
  else if (o == 64) { *row = P.rsW;               *bias = P.rsb[0]; }
  else if (o == 65) { *row = P.rgW;               *bias = P.rgb[0]; }
  else if (o == 66) { *row = P.rgammaW;           *bias = P.rgammab[0]; }
  else if (o < 131) { *row = P.wkW + (o-67)*Cv;   *bias = P.wkb[o-67]; }
  else if (o == 131){ *row = P.wsW;               *bias = P.wsb[0]; }
  else if (o < 196) { *row = P.weW + (o-132)*Cv;  *bias = P.web[o-132]; }
  else              { *row = P.waW + (o-196)*Cv;  *bias = P.wab[o-196]; }
}

__device__ inline void gbar(int* cnt, int* gen){
  __syncthreads();
  if (threadIdx.x == 0){
    __threadfence();
    int g = __hip_atomic_load(gen, __ATOMIC_RELAXED, __HIP_MEMORY_SCOPE_AGENT);
    int a = __hip_atomic_fetch_add(cnt, 1, __ATOMIC_ACQ_REL, __HIP_MEMORY_SCOPE_AGENT);
    if (a == NBLK-1){
      __hip_atomic_store(cnt, 0, __ATOMIC_RELAXED, __HIP_MEMORY_SCOPE_AGENT);
      __hip_atomic_fetch_add(gen, 1, __ATOMIC_RELEASE, __HIP_MEMORY_SCOPE_AGENT);
    } else {
      while (__hip_atomic_load(gen, __ATOMIC_RELAXED, __HIP_MEMORY_SCOPE_AGENT) == g)
        __builtin_amdgcn_s_sleep(4);
    }
    __threadfence();
  }
  __syncthreads();
}

__global__ __launch_bounds__(NTHR) void ntm_kernel(KP P){
  __shared__ unsigned Wg[8][420];      // packed bf16 gate-weight rows (416 used, pad for banks)
  __shared__ float gbias[8];
  __shared__ float memL[128][65];      // this block's memory slice, padded
  __shared__ float headW[2][512];
  __shared__ float headb[2];
  __shared__ float outWrow[576];
  __shared__ float outbj[1];
  __shared__ float gatebuf[32][8];
  __shared__ float cstate[32][2];
  __shared__ float knr[64], knw[64];
  __shared__ float scal[8];
  __shared__ float fwL[128], wwL[128];
  __shared__ float erL[64], adL[64];
  __shared__ float red[32][8];
  __shared__ float rvpart[4][64];

  const int tid = threadIdx.x;
  const int bid = blockIdx.x;
  float* wsf = P.ws;
  int* cnt = (int*)P.ws;
  int* gen = (int*)P.ws + 64;
  float* heads = wsf + HEADOFF;
  const int b = bid & 31;    // batch group (same-b blocks share XCD under %8 round-robin)
  const int k = bid >> 5;    // n-slice index (128 rows)

  // ---------------- startup: load persistent LDS ----------------
  for (int idx = tid; idx < 8*416; idx += NTHR){
    int rl = idx / 416, u = idx % 416;
    int r = (rl>>1)*Cv + 2*bid + (rl&1);   // rl = gate*2 + clocal
    float a, b2;
    if (u < 160){ a = P.Wih[r*320 + 2*u];      b2 = P.Wih[r*320 + 2*u + 1]; }
    else        { int q = 2*(u-160); a = P.Whh[r*512 + q]; b2 = P.Whh[r*512 + q + 1]; }
    Wg[rl][u] = packbf(a, b2);
  }
  if (tid < 8){
    int rl = tid; int r = (rl>>1)*Cv + 2*bid + (rl&1);
    gbias[rl] = P.bih[r] + P.bhh[r];
  }
  for (int rep = 0; rep < 2; ++rep){
    int o = bid + rep*256;
    if (rep == 0 || bid < 4){
      const float* row; float bias; head_src(P, o, &row, &bias);
      for (int q = tid; q < 512; q += NTHR) headW[rep][q] = row[q];
      if (tid == 0) headb[rep] = bias;
    }
  }
  for (int q = tid; q < 576; q += NTHR) outWrow[q] = P.outW[bid*576 + q];
  if (tid == 0) outbj[0] = P.outb[bid];
  for (int idx = tid; idx < 128*65; idx += NTHR) ((float*)memL)[idx] = 0.f;
  if (tid < 64) cstate[tid>>1][tid&1] = 0.f;
  __syncthreads();

  float er = 0.f, eg = 0.f, ew = 0.f;   // live across P3->P4 barrier in registers

  for (int t = 0; t < Sv; ++t){
    // ================= P1: gates + h/c update + out-proj(t-1) =================
    const float* hprev = wsf + HOFF + ((t+1)&1)*Bv*Cv;
    {
      const int bb = tid >> 3, rl = tid & 7;
      float acc = gbias[rl];
      const float* xb = P.x + ((size_t)bb*Sv + (size_t)t)*Iv;
      #pragma unroll 8
      for (int u = 0; u < 128; u += 2){
        uint2 w = *(const uint2*)&Wg[rl][u];
        float4 xv = *(const float4*)(xb + 2*u);
        acc += blo(w.x)*xv.x + bhi(w.x)*xv.y + blo(w.y)*xv.z + bhi(w.y)*xv.w;
      }
      const float* rvb = wsf + RVOFF + bb*Vv;
      #pragma unroll 8
      for (int u = 0; u < 32; u += 2){
        uint2 w = *(const uint2*)&Wg[rl][128+u];
        float4 xv = *(const float4*)(rvb + 2*u);
        acc += blo(w.x)*xv.x + bhi(w.x)*xv.y + blo(w.y)*xv.z + bhi(w.y)*xv.w;
      }
      const float* hb = hprev + bb*Cv;
      #pragma unroll 8
      for (int u = 0; u < 256; u += 2){
        uint2 w = *(const uint2*)&Wg[rl][160+u];
        float4 hv = *(const float4*)(hb + 2*u);
        acc += blo(w.x)*hv.x + bhi(w.x)*hv.y + blo(w.y)*hv.z + bhi(w.y)*hv.w;
      }
      gatebuf[bb][rl] = acc;
    }
    __syncthreads();
    if (tid < 64){
      int bb2 = tid >> 1, cl = tid & 1;
      float ig = gatebuf[bb2][cl],   fg = gatebuf[bb2][2+cl];
      float gg = gatebuf[bb2][4+cl], og = gatebuf[bb2][6+cl];
      float c = cstate[bb2][cl];
      c = sigf(fg)*c + sigf(ig)*tanhf(gg);
      float h = sigf(og)*tanhf(c);
      cstate[bb2][cl] = c;
      wsf[HOFF + (t&1)*Bv*Cv + bb2*Cv + 2*bid + cl] = h;
    }
    if (t > 0){
      int bb = tid >> 3, kc = tid & 7;
      const float* hp = hprev + bb*Cv;
      const float* rvb = wsf + RVOFF + bb*Vv;
      float p = 0.f;
      int q0 = kc*72;
      for (int q = q0; q < q0+72; ++q){
        float vv = (q < Cv) ? hp[q] : rvb[q-Cv];
        p += outWrow[q]*vv;
      }
      red[bb][kc] = p;
      __syncthreads();
      if (tid < 32){
        float s2 = outbj[0];
        #pragma unroll
        for (int k2 = 0; k2 < 8; ++k2) s2 += red[tid][k2];
        P.out[((size_t)tid*Sv + (t-1))*Ov + bid] = s2;
      }
    }
    gbar(cnt, gen);

    // ================= P2: head linears (distributed) + zero accumulators =================
    const float* hcur = wsf + HOFF + (t&1)*Bv*Cv;
    for (int rep = 0; rep < 2; ++rep){
      bool active = (rep == 0) || (bid < 4);
      int o = bid + rep*256;
      float p = 0.f;
      if (active){
        int bb = tid >> 3, kc = tid & 7;
        const float* hb = hcur + bb*Cv;
        #pragma unroll 8
        for (int q = kc*64; q < kc*64+64; ++q) p += headW[rep][q]*hb[q];
      }
      __syncthreads();
      if (active){ int bb = tid >> 3, kc = tid & 7; red[bb][kc] = p; }
      __syncthreads();
      if (active && tid < 32){
        float s2 = headb[rep];
        #pragma unroll
        for (int k2 = 0; k2 < 8; ++k2) s2 += red[tid][k2];
        heads[o*32 + tid] = headact(o, s2);
      }
      __syncthreads();
    }
    if (bid < 32){
      if (tid < 64) wsf[RVOFF + bid*Vv + tid] = 0.f;
      if (tid < 8)  wsf[SUMOFF + bid*8 + tid] = 0.f;
    }
    gbar(cnt, gen);

    // ================= P3: content addressing (sim -> e) + partial sums =================
    if (tid < 64){
      float kr = heads[tid*32 + b], kw = heads[(67+tid)*32 + b];
      float sr = kr*kr, sw = kw*kw;
      #pragma unroll
      for (int off = 32; off; off >>= 1){ sr += __shfl_xor(sr, off); sw += __shfl_xor(sw, off); }
      float inr = 1.f/fmaxf(sqrtf(sr), 1e-12f), inw = 1.f/fmaxf(sqrtf(sw), 1e-12f);
      knr[tid] = kr*inr; knw[tid] = kw*inw;
      if (tid == 0){
        scal[0] = heads[64*32 + b];   // str_r
        scal[1] = heads[65*32 + b];   // gate
        scal[2] = heads[66*32 + b];   // gamma
        scal[3] = heads[131*32 + b];  // str_w
      }
    }
    __syncthreads();
    er = 0.f; eg = 0.f; ew = 0.f;
    {
      float str_r = scal[0], gamma = scal[2], str_w = scal[3];
      if (tid < 128){
        float dr = 0.f, dw = 0.f, nn = 0.f;
        #pragma unroll 8
        for (int v = 0; v < 64; ++v){
          float m = memL[tid][v];
          dr += m*knr[v]; dw += m*knw[v]; nn += m*m;
        }
        float innm = 1.f/fmaxf(sqrtf(nn), 1e-12f);
        float tr = str_r*(dr*innm - 1.f);           // shifted: softmax-invariant
        er = expf(tr);
        eg = expf(gamma*tr);                         // (e^tr)^gamma
        ew = expf(str_w*(dw*innm - 1.f));
      }
      float s0 = er, s1 = eg, s2 = ew;
      #pragma unroll
      for (int off = 32; off; off >>= 1){
        s0 += __shfl_xor(s0, off); s1 += __shfl_xor(s1, off); s2 += __shfl_xor(s2, off);
      }
      if ((tid & 63) == 0 && tid < 128){
        int w2 = tid >> 6; red[w2][0] = s0; red[w2][1] = s1; red[w2][2] = s2;
      }
      __syncthreads();
      if (tid == 0){
        atomicAdd(&wsf[SUMOFF + b*8 + 0], red[0][0] + red[1][0]);
        atomicAdd(&wsf[SUMOFF + b*8 + 1], red[0][1] + red[1][1]);
        atomicAdd(&wsf[SUMOFF + b*8 + 2], red[0][2] + red[1][2]);
      }
    }
    gbar(cnt, gen);

    // ================= P4: fw, read-vector, memory update =================
    if (tid == 0){
      scal[4] = wsf[SUMOFF + b*8 + 0];
      scal[5] = wsf[SUMOFF + b*8 + 1];
      scal[6] = wsf[SUMOFF + b*8 + 2];
    }
    if (tid < 64){
      erL[tid] = heads[(132+tid)*32 + b];
      adL[tid] = heads[(196+tid)*32 + b];
    }
    __syncthreads();
    {
      float Se = scal[4], Sg = scal[5], Sw = scal[6], gate_s = scal[1];
      if (tid < 128){
        fwL[tid] = gate_s*(eg/Sg) + (1.f - gate_s)*(er/Se);
        wwL[tid] = ew/Sw;
      }
    }
    __syncthreads();
    {
      int v = tid & 63, cc = tid >> 6;
      float p = 0.f;
      #pragma unroll 8
      for (int j = 0; j < 32; ++j){ int r = cc*32 + j; p += fwL[r]*memL[r][v]; }
      rvpart[cc][v] = p;
    }
    __syncthreads();
    if (tid < 64)
      atomicAdd(&wsf[RVOFF + b*Vv + tid],
                rvpart[0][tid] + rvpart[1][tid] + rvpart[2][tid] + rvpart[3][tid]);
    #pragma unroll 4
    for (int e2 = 0; e2 < 32; ++e2){
      int flat = tid + e2*256;
      int r = flat >> 6, v2 = flat & 63;
      memL[r][v2] = memL[r][v2]*(1.f - wwL[r]*erL[v2]) + wwL[r]*adL[v2];
    }
    gbar(cnt, gen);
  }

  // ================= epilogue: out-proj for t = S-1 =================
  {
    const float* hp = wsf + HOFF + ((Sv-1)&1)*Bv*Cv;
    int bb = tid >> 3, kc = tid & 7;
    const float* hb2 = hp + bb*Cv;
    const float* rvb = wsf + RVOFF + bb*Vv;
    float p = 0.f; int q0 = kc*72;
    for (int q = q0; q < q0+72; ++q){
      float vv = (q < Cv) ? hb2[q] : rvb[q-Cv];
      p += outWrow[q]*vv;
    }
    red[bb][kc] = p;
    __syncthreads();
    if (tid < 32){
      float s2 = outbj[0];
      #pragma unroll
      for (int k2 = 0; k2 < 8; ++k2) s2 += red[tid][k2];
      P.out[((size_t)tid*Sv + (Sv-1))*Ov + bid] = s2;
    }
  }
  // ================= epilogue: final memory writeout =================
  for (int e2 = 0; e2 < 32; ++e2){
    int flat = tid + e2*256;
    int r = flat >> 6, v2 = flat & 63;
    P.memout[((size_t)b*Nv + (size_t)k*128 + r)*Vv + v2] = memL[r][v2];
  }
}

extern "C" void kernel_launch(void* const* d_in, const int* in_sizes, int n_in,
                              void* d_out, int out_size, void* d_ws, size_t ws_size,
                              hipStream_t stream) {
  (void)in_sizes; (void)n_in; (void)out_size; (void)ws_size;
  KP p;
  p.x       = (const float*)d_in[0];
  p.Wih     = (const float*)d_in[1];
  p.Whh     = (const float*)d_in[2];
  p.bih     = (const float*)d_in[3];
  p.bhh     = (const float*)d_in[4];
  p.rkW     = (const float*)d_in[5];  p.rkb     = (const float*)d_in[6];
  p.rsW     = (const float*)d_in[7];  p.rsb     = (const float*)d_in[8];
  p.rgW     = (const float*)d_in[9];  p.rgb     = (const float*)d_in[10];
  // d_in[11], d_in[12]: r_shift_W/b — computed-but-unused in reference; skipped
  p.rgammaW = (const float*)d_in[13]; p.rgammab = (const float*)d_in[14];
  p.wkW     = (const float*)d_in[15]; p.wkb     = (const float*)d_in[16];
  p.wsW     = (const float*)d_in[17]; p.wsb     = (const float*)d_in[18];
  p.weW     = (const float*)d_in[19]; p.web     = (const float*)d_in[20];
  p.waW     = (const float*)d_in[21]; p.wab     = (const float*)d_in[22];
  p.outW    = (const float*)d_in[23]; p.outb    = (const float*)d_in[24];
  p.out     = (float*)d_out;
  p.memout  = (float*)d_out + (size_t)Bv*Sv*Ov;
  p.ws      = (float*)d_ws;

  hipMemsetAsync(d_ws, 0, ZERO_BYTES, stream);   // barrier counters + h/rv/sums
  hipLaunchKernelGGL(ntm_kernel, dim3(NBLK), dim3(NTHR), 0, stream, p);
}

// Round 3
// 9674.902 us; speedup vs baseline: 1.9619x; 1.9619x over previous
//
#include <hip/hip_runtime.h>

#define Bv 32
#define Sv 256
#define Iv 256
#define Cv 512
#define Nv 1024
#define Vv 64
#define Ov 256
#define NBLK 256
#define NTHR 256

// ws float-index layout (all cross-block data accessed with sc1 coherent ops)
#define CNTOFF  0                         // barrier counter (int), own cacheline
#define RVOFF   64                        // rv[32][64] fp32 (atomicAdd accumulator)
#define SUMOFF  (RVOFF + Bv*Vv)           // 2112: sums[32][8] fp32
#define HUOFF   (SUMOFF + Bv*8)           // 2368: h packed bf16x2, uint[32][256]
#define HEADOFF (HUOFF + Bv*256)          // 10560: heads[32][264] fp32 (b-major)
#define ZERO_BYTES (HUOFF * 4)            // zero cnt + rv + sums

struct KP {
  const float *x, *Wih, *Whh, *bih, *bhh;
  const float *rkW, *rkb, *rsW, *rsb, *rgW, *rgb, *rgammaW, *rgammab;
  const float *wkW, *wkb, *wsW, *wsb, *weW, *web, *waW, *wab;
  const float *outW, *outb;
  float *out;
  float *memout;
  float *ws;
};

__device__ inline float sigf(float x){ return 1.f/(1.f+expf(-x)); }
__device__ inline float softplusf(float x){ return fmaxf(x,0.f) + log1pf(expf(-fabsf(x))); }
__device__ inline float blo(unsigned u){ return __uint_as_float(u<<16); }
__device__ inline float bhi(unsigned u){ return __uint_as_float(u & 0xffff0000u); }
__device__ inline unsigned short f2bf(float f){
  unsigned u = __float_as_uint(f);
  return (unsigned short)((u + 0x7fffu + ((u>>16)&1u)) >> 16);
}
__device__ inline unsigned packbf(float a, float b){
  return (unsigned)f2bf(a) | ((unsigned)f2bf(b) << 16);
}

// ---- agent-coherent (MALL) access helpers: no cache-maintenance ops ----
__device__ inline void stc_f(float* p, float v){
  asm volatile("global_store_dword %0, %1, off sc1" :: "v"(p), "v"(v) : "memory");
}
__device__ inline void stc_u(unsigned* p, unsigned v){
  asm volatile("global_store_dword %0, %1, off sc1" :: "v"(p), "v"(v) : "memory");
}
#define LDC4F(dst, addr) asm volatile("global_load_dwordx4 %0, %1, off sc1" : "=v"(dst) : "v"(addr) : "memory")
#define LDC4U(dst, addr) asm volatile("global_load_dwordx4 %0, %1, off sc1" : "=v"(dst) : "v"(addr) : "memory")
#define LDCF(dst, addr)  asm volatile("global_load_dword %0, %1, off sc1"  : "=v"(dst) : "v"(addr) : "memory")
#define WAITV do { asm volatile("s_waitcnt vmcnt(0)" ::: "memory"); __builtin_amdgcn_sched_barrier(0); } while(0)

__device__ inline float headact(int o, float s){
  if (o < 64)  return tanhf(s);
  if (o == 64) return softplusf(s);
  if (o == 65) return sigf(s);
  if (o == 66) return 1.f + softplusf(s);
  if (o < 131) return tanhf(s);
  if (o == 131) return softplusf(s);
  if (o < 196) return sigf(s);
  return tanhf(s);
}

__device__ inline void head_src(const KP& P, int o, const float** row, float* bias){
  if (o < 64)       { *row = P.rkW + o*Cv;        *bias = P.rkb[o]; }
  else if (o == 64) { *row = P.rsW;               *bias = P.rsb[0]; }
  else if (o == 65) { *row = P.rgW;               *bias = P.rgb[0]; }
  else if (o == 66) { *row = P.rgammaW;           *bias = P.rgammab[0]; }
  else if (o < 131) { *row = P.wkW + (o-67)*Cv;   *bias = P.wkb[o-67]; }
  else if (o == 131){ *row = P.wsW;               *bias = P.wsb[0]; }
  else if (o < 196) { *row = P.weW + (o-132)*Cv;  *bias = P.web[o-132]; }
  else              { *row = P.waW + (o-196)*Cv;  *bias = P.wab[o-196]; }
}

// monotonic-counter global barrier with watchdog: no reset, no fences.
// Watchdog: if ~3e8 realtime ticks (~3s) elapse, break out (turns a potential
// deadlock into an absmax failure instead of a wedged container).
__device__ inline void gbar(int* cnt, int target, unsigned long long t0){
  asm volatile("s_waitcnt vmcnt(0)" ::: "memory");   // drain sc1 stores/atomics (all waves)
  __syncthreads();
  if (threadIdx.x == 0){
    int a = __hip_atomic_fetch_add(cnt, 1, __ATOMIC_RELAXED, __HIP_MEMORY_SCOPE_AGENT);
    if (a != target - 1){
      unsigned sp = 0;
      while (__hip_atomic_load(cnt, __ATOMIC_RELAXED, __HIP_MEMORY_SCOPE_AGENT) < target){
        __builtin_amdgcn_s_sleep(2);
        if (((++sp) & 1023u) == 0u &&
            (__builtin_amdgcn_s_memrealtime() - t0) > 300000000ULL) break;
      }
    }
  }
  __syncthreads();
}

__global__ __launch_bounds__(NTHR) void ntm_kernel(KP P){
  __shared__ unsigned Wg[8][420];     // packed bf16 gate-weight rows
  __shared__ float gbias[8];
  __shared__ float memL[128][65];     // block's memory slice fp32, padded
  __shared__ unsigned hL[32][260];    // staged h, packed bf16 pairs, padded
  __shared__ float rvL[32][68];       // staged rv fp32, padded
  __shared__ float headW[2][512];
  __shared__ float headb[2];
  __shared__ float outWrow[576];
  __shared__ float outbj[1];
  __shared__ float gatebuf[32][9];
  __shared__ float knr[64], knw[64];
  __shared__ float scal[8];
  __shared__ float fwL[128], wwL[128];
  __shared__ float erL[64], adL[64];
  __shared__ float red[32][9];
  __shared__ float rvpart[4][64];

  const int tid = threadIdx.x;
  const int bid = blockIdx.x;
  float* wsf = P.ws;
  int* cnt = (int*)P.ws;
  unsigned* hu = (unsigned*)P.ws + HUOFF;
  const int b = bid & 31;
  const int k = bid >> 5;
  const float* headsb = wsf + HEADOFF + b*264;
  float* headsw = wsf + HEADOFF;
  const unsigned long long t0 = __builtin_amdgcn_s_memrealtime();

  // ---------------- startup ----------------
  for (int idx = tid; idx < 8*416; idx += NTHR){
    int rl = idx / 416, u = idx % 416;
    int r = (rl>>1)*Cv + 2*bid + (rl&1);
    float a, b2;
    if (u < 160){ a = P.Wih[r*320 + 2*u];      b2 = P.Wih[r*320 + 2*u + 1]; }
    else        { int q = 2*(u-160); a = P.Whh[r*512 + q]; b2 = P.Whh[r*512 + q + 1]; }
    Wg[rl][u] = packbf(a, b2);
  }
  if (tid < 8){
    int rl = tid; int r = (rl>>1)*Cv + 2*bid + (rl&1);
    gbias[rl] = P.bih[r] + P.bhh[r];
  }
  for (int rep = 0; rep < 2; ++rep){
    int o = bid + rep*256;
    if (rep == 0 || bid < 4){
      const float* row; float bias; head_src(P, o, &row, &bias);
      for (int q = tid; q < 512; q += NTHR) headW[rep][q] = row[q];
      if (tid == 0) headb[rep] = bias;
    }
  }
  for (int q = tid; q < 576; q += NTHR) outWrow[q] = P.outW[bid*576 + q];
  if (tid == 0) outbj[0] = P.outb[bid];
  for (int idx = tid; idx < 128*65; idx += NTHR) ((float*)memL)[idx] = 0.f;
  for (int idx = tid; idx < 32*260; idx += NTHR) ((unsigned*)hL)[idx] = 0u;
  __syncthreads();

  float c0 = 0.f, c1 = 0.f;             // LSTM cell state (tid<32)
  float er = 0.f, eg = 0.f, ew = 0.f;   // live P3->P4
  int barn = 0;

  for (int t = 0; t < Sv; ++t){
    // ===== P1: stage rv, gate GEMM, h/c update, out-proj(t-1) =====
    {
      float4 r0, r1;
      const float* rs = wsf + RVOFF + tid*4;
      LDC4F(r0, rs);
      LDC4F(r1, rs + 1024);
      WAITV;
      int rr = tid >> 4, rc = (tid & 15) * 4;
      *(float4*)&rvL[rr][rc] = r0;
      *(float4*)&rvL[16+rr][rc] = r1;
    }
    __syncthreads();
    {
      const int bb = tid >> 3, rl = tid & 7;
      float acc = gbias[rl];
      const float* xb = P.x + ((size_t)bb*Sv + (size_t)t)*Iv;
      #pragma unroll 8
      for (int u = 0; u < 128; u += 2){
        uint2 w = *(const uint2*)&Wg[rl][u];
        float4 xv = *(const float4*)(xb + 2*u);
        acc += blo(w.x)*xv.x + bhi(w.x)*xv.y + blo(w.y)*xv.z + bhi(w.y)*xv.w;
      }
      #pragma unroll 8
      for (int u = 0; u < 32; u += 2){
        uint2 w = *(const uint2*)&Wg[rl][128+u];
        float4 xv = *(const float4*)&rvL[bb][2*u];
        acc += blo(w.x)*xv.x + bhi(w.x)*xv.y + blo(w.y)*xv.z + bhi(w.y)*xv.w;
      }
      #pragma unroll 8
      for (int u = 0; u < 256; u += 2){
        uint2 w = *(const uint2*)&Wg[rl][160+u];
        uint2 hp = *(const uint2*)&hL[bb][u];
        acc += blo(w.x)*blo(hp.x) + bhi(w.x)*bhi(hp.x)
             + blo(w.y)*blo(hp.y) + bhi(w.y)*bhi(hp.y);
      }
      gatebuf[bb][rl] = acc;
    }
    __syncthreads();
    if (tid < 32){
      float ig0=gatebuf[tid][0], ig1=gatebuf[tid][1];
      float fg0=gatebuf[tid][2], fg1=gatebuf[tid][3];
      float gg0=gatebuf[tid][4], gg1=gatebuf[tid][5];
      float og0=gatebuf[tid][6], og1=gatebuf[tid][7];
      c0 = sigf(fg0)*c0 + sigf(ig0)*tanhf(gg0);
      c1 = sigf(fg1)*c1 + sigf(ig1)*tanhf(gg1);
      float h0 = sigf(og0)*tanhf(c0);
      float h1 = sigf(og1)*tanhf(c1);
      stc_u(&hu[tid*256 + bid], packbf(h0, h1));
    }
    if (t > 0){
      int bb2 = tid >> 3, kc = tid & 7;
      float p = 0.f;
      if (kc < 7){
        int j0 = kc*36;
        #pragma unroll
        for (int j = 0; j < 36; ++j){
          unsigned u = hL[bb2][j0+j];
          p += blo(u)*outWrow[2*(j0+j)] + bhi(u)*outWrow[2*(j0+j)+1];
        }
      } else {
        #pragma unroll
        for (int j = 252; j < 256; ++j){
          unsigned u = hL[bb2][j];
          p += blo(u)*outWrow[2*j] + bhi(u)*outWrow[2*j+1];
        }
        #pragma unroll 16
        for (int v = 0; v < 64; ++v) p += outWrow[512+v]*rvL[bb2][v];
      }
      red[bb2][kc] = p;
      __syncthreads();
      if (tid < 32){
        float s2 = outbj[0];
        #pragma unroll
        for (int k2 = 0; k2 < 8; ++k2) s2 += red[tid][k2];
        P.out[((size_t)tid*Sv + (t-1))*Ov + bid] = s2;
      }
    }
    gbar(cnt, (++barn)*NBLK, t0);

    // ===== P2: stage h(t), head linears, zero accumulators =====
    {
      uint4 q0,q1,q2,q3,q4,q5,q6,q7;
      const unsigned* hs = hu + tid*4;
      LDC4U(q0, hs + 0*1024); LDC4U(q1, hs + 1*1024);
      LDC4U(q2, hs + 2*1024); LDC4U(q3, hs + 3*1024);
      LDC4U(q4, hs + 4*1024); LDC4U(q5, hs + 5*1024);
      LDC4U(q6, hs + 6*1024); LDC4U(q7, hs + 7*1024);
      WAITV;
      int sr = tid >> 6, sc = (tid & 63) * 4;
      *(uint4*)&hL[ 0+sr][sc] = q0; *(uint4*)&hL[ 4+sr][sc] = q1;
      *(uint4*)&hL[ 8+sr][sc] = q2; *(uint4*)&hL[12+sr][sc] = q3;
      *(uint4*)&hL[16+sr][sc] = q4; *(uint4*)&hL[20+sr][sc] = q5;
      *(uint4*)&hL[24+sr][sc] = q6; *(uint4*)&hL[28+sr][sc] = q7;
    }
    __syncthreads();
    for (int rep = 0; rep < 2; ++rep){
      bool active = (rep == 0) || (bid < 4);
      int o = bid + rep*256;
      float p = 0.f;
      if (active){
        int bb = tid >> 3, kc = tid & 7;
        #pragma unroll
        for (int j = 0; j < 32; ++j){
          unsigned u = hL[bb][kc + 8*j];
          int q = 2*(kc + 8*j);
          p += blo(u)*headW[rep][q] + bhi(u)*headW[rep][q+1];
        }
      }
      __syncthreads();
      if (active){ red[tid>>3][tid&7] = p; }
      __syncthreads();
      if (active && tid < 32){
        float s2 = headb[rep];
        #pragma unroll
        for (int k2 = 0; k2 < 8; ++k2) s2 += red[tid][k2];
        stc_f(&headsw[tid*264 + o], headact(o, s2));
      }
      __syncthreads();
    }
    if (bid < 32){
      if (tid < 64) stc_f(&wsf[RVOFF + bid*Vv + tid], 0.f);
      if (tid < 8)  stc_f(&wsf[SUMOFF + bid*8 + tid], 0.f);
    }
    gbar(cnt, (++barn)*NBLK, t0);

    // ===== P3: content addressing + partial sums =====
    {
      float kr = 0.f, kw = 0.f, s_r = 0.f, s_g = 0.f, s_gam = 0.f, s_sw = 0.f;
      if (tid < 64){
        LDCF(kr, headsb + tid);
        LDCF(kw, headsb + 67 + tid);
      }
      if (tid == 0){
        LDCF(s_r, headsb + 64);  LDCF(s_g, headsb + 65);
        LDCF(s_gam, headsb + 66); LDCF(s_sw, headsb + 131);
      }
      WAITV;
      if (tid < 64){
        float sr = kr*kr, sw2 = kw*kw;
        #pragma unroll
        for (int off = 32; off; off >>= 1){ sr += __shfl_xor(sr, off); sw2 += __shfl_xor(sw2, off); }
        knr[tid] = kr * (1.f/fmaxf(sqrtf(sr), 1e-12f));
        knw[tid] = kw * (1.f/fmaxf(sqrtf(sw2), 1e-12f));
        if (tid == 0){ scal[0]=s_r; scal[1]=s_g; scal[2]=s_gam; scal[3]=s_sw; }
      }
    }
    __syncthreads();
    er = 0.f; eg = 0.f; ew = 0.f;
    {
      float str_r = scal[0], gamma = scal[2], str_w = scal[3];
      if (tid < 128){
        float dr = 0.f, dw = 0.f, nn = 0.f;
        #pragma unroll 8
        for (int v = 0; v < 64; ++v){
          float m = memL[tid][v];
          dr += m*knr[v]; dw += m*knw[v]; nn += m*m;
        }
        float innm = 1.f/fmaxf(sqrtf(nn), 1e-12f);
        float tr = str_r*(dr*innm - 1.f);
        er = expf(tr);
        eg = expf(gamma*tr);
        ew = expf(str_w*(dw*innm - 1.f));
      }
      float s0 = er, s1 = eg, s2 = ew;
      #pragma unroll
      for (int off = 32; off; off >>= 1){
        s0 += __shfl_xor(s0, off); s1 += __shfl_xor(s1, off); s2 += __shfl_xor(s2, off);
      }
      if ((tid & 63) == 0 && tid < 128){
        int w2 = tid >> 6; red[w2][0] = s0; red[w2][1] = s1; red[w2][2] = s2;
      }
      __syncthreads();
      if (tid == 0){
        atomicAdd(&wsf[SUMOFF + b*8 + 0], red[0][0] + red[1][0]);
        atomicAdd(&wsf[SUMOFF + b*8 + 1], red[0][1] + red[1][1]);
        atomicAdd(&wsf[SUMOFF + b*8 + 2], red[0][2] + red[1][2]);
      }
    }
    gbar(cnt, (++barn)*NBLK, t0);

    // ===== P4: fw, read-vector, memory update =====
    {
      float Se = 0.f, Sg = 0.f, Sw = 0.f, erv = 0.f, adv = 0.f;
      const float* sb = wsf + SUMOFF + b*8;
      if (tid == 0){ LDCF(Se, sb+0); LDCF(Sg, sb+1); LDCF(Sw, sb+2); }
      if (tid < 64){
        LDCF(erv, headsb + 132 + tid);
        LDCF(adv, headsb + 196 + tid);
      }
      WAITV;
      if (tid == 0){ scal[4]=Se; scal[5]=Sg; scal[6]=Sw; }
      if (tid < 64){ erL[tid] = erv; adL[tid] = adv; }
    }
    __syncthreads();
    {
      float Se = scal[4], Sg = scal[5], Sw = scal[6], gate_s = scal[1];
      if (tid < 128){
        fwL[tid] = gate_s*(eg/Sg) + (1.f - gate_s)*(er/Se);
        wwL[tid] = ew/Sw;
      }
    }
    __syncthreads();
    {
      int v = tid & 63, cc = tid >> 6;
      float p = 0.f;
      #pragma unroll 8
      for (int j = 0; j < 32; ++j){ int r = cc*32 + j; p += fwL[r]*memL[r][v]; }
      rvpart[cc][v] = p;
    }
    __syncthreads();
    if (tid < 64)
      atomicAdd(&wsf[RVOFF + b*Vv + tid],
                rvpart[0][tid] + rvpart[1][tid] + rvpart[2][tid] + rvpart[3][tid]);
    #pragma unroll 4
    for (int e2 = 0; e2 < 32; ++e2){
      int flat = tid + e2*256;
      int r = flat >> 6, v2 = flat & 63;
      memL[r][v2] = memL[r][v2]*(1.f - wwL[r]*erL[v2]) + wwL[r]*adL[v2];
    }
    gbar(cnt, (++barn)*NBLK, t0);
  }

  // ===== epilogue: out-proj(S-1) =====
  {
    float4 r0, r1;
    const float* rs = wsf + RVOFF + tid*4;
    LDC4F(r0, rs);
    LDC4F(r1, rs + 1024);
    WAITV;
    int rr = tid >> 4, rc = (tid & 15) * 4;
    *(float4*)&rvL[rr][rc] = r0;
    *(float4*)&rvL[16+rr][rc] = r1;
  }
  __syncthreads();
  {
    int bb2 = tid >> 3, kc = tid & 7;
    float p = 0.f;
    if (kc < 7){
      int j0 = kc*36;
      #pragma unroll
      for (int j = 0; j < 36; ++j){
        unsigned u = hL[bb2][j0+j];
        p += blo(u)*outWrow[2*(j0+j)] + bhi(u)*outWrow[2*(j0+j)+1];
      }
    } else {
      #pragma unroll
      for (int j = 252; j < 256; ++j){
        unsigned u = hL[bb2][j];
        p += blo(u)*outWrow[2*j] + bhi(u)*outWrow[2*j+1];
      }
      #pragma unroll 16
      for (int v = 0; v < 64; ++v) p += outWrow[512+v]*rvL[bb2][v];
    }
    red[bb2][kc] = p;
    __syncthreads();
    if (tid < 32){
      float s2 = outbj[0];
      #pragma unroll
      for (int k2 = 0; k2 < 8; ++k2) s2 += red[tid][k2];
      P.out[((size_t)tid*Sv + (Sv-1))*Ov + bid] = s2;
    }
  }
  // ===== epilogue: final memory writeout =====
  for (int e2 = 0; e2 < 32; ++e2){
    int flat = tid + e2*256;
    int r = flat >> 6, v2 = flat & 63;
    P.memout[((size_t)b*Nv + (size_t)k*128 + r)*Vv + v2] = memL[r][v2];
  }
}

extern "C" void kernel_launch(void* const* d_in, const int* in_sizes, int n_in,
                              void* d_out, int out_size, void* d_ws, size_t ws_size,
                              hipStream_t stream) {
  (void)in_sizes; (void)n_in; (void)out_size; (void)ws_size;
  KP p;
  p.x       = (const float*)d_in[0];
  p.Wih     = (const float*)d_in[1];
  p.Whh     = (const float*)d_in[2];
  p.bih     = (const float*)d_in[3];
  p.bhh     = (const float*)d_in[4];
  p.rkW     = (const float*)d_in[5];  p.rkb     = (const float*)d_in[6];
  p.rsW     = (const float*)d_in[7];  p.rsb     = (const float*)d_in[8];
  p.rgW     = (const float*)d_in[9];  p.rgb     = (const float*)d_in[10];
  p.rgammaW = (const float*)d_in[13]; p.rgammab = (const float*)d_in[14];
  p.wkW     = (const float*)d_in[15]; p.wkb     = (const float*)d_in[16];
  p.wsW     = (const float*)d_in[17]; p.wsb     = (const float*)d_in[18];
  p.weW     = (const float*)d_in[19]; p.web     = (const float*)d_in[20];
  p.waW     = (const float*)d_in[21]; p.wab     = (const float*)d_in[22];
  p.outW    = (const float*)d_in[23]; p.outb    = (const float*)d_in[24];
  p.out     = (float*)d_out;
  p.memout  = (float*)d_out + (size_t)Bv*Sv*Ov;
  p.ws      = (float*)d_ws;

  hipMemsetAsync(d_ws, 0, ZERO_BYTES, stream);
  hipLaunchKernelGGL(ntm_kernel, dim3(NBLK), dim3(NTHR), 0, stream, p);
}

// Round 5
// 7055.325 us; speedup vs baseline: 2.6903x; 1.3713x over previous
//
#include <hip/hip_runtime.h>

#define Bv 32
#define Sv 256
#define Iv 256
#define Cv 512
#define Nv 1024
#define Vv 64
#define Ov 256
#define NBLK 256
#define NTHR 256

// ---- ws layout ----
// int region (16KB): barrier lines, 64B-spaced
#define ROOT_I   0
#define GA_I(b)  (64 + 16*(b))      // group arrive
#define REL_I(b) (576 + 16*(b))     // group release flag
#define PBC_I(b) (1088 + 16*(b))    // per-b barrier counter
// float region
#define RVBASE   4096               // rv[2][32][64]
#define SUMBASE  (RVBASE + 2*Bv*Vv)         // 8192: sums[2][32][8]
#define HUBASE   (SUMBASE + 2*Bv*8)         // 8704: h packed bf16x2, uint[2][32][256]
#define HEADBASE (HUBASE + 2*Bv*256)        // 25088: heads[32][264]
#define ZERO_BYTES (HUBASE*4 + 2*Bv*256*4)  // zero ints+rv+sums+hu = 25088*4

struct KP {
  const float *x, *Wih, *Whh, *bih, *bhh;
  const float *rkW, *rkb, *rsW, *rsb, *rgW, *rgb, *rgammaW, *rgammab;
  const float *wkW, *wkb, *wsW, *wsb, *weW, *web, *waW, *wab;
  const float *outW, *outb;
  float *out;
  float *memout;
  float *ws;
};

__device__ inline float sigf(float x){ return 1.f/(1.f+expf(-x)); }
__device__ inline float softplusf(float x){ return fmaxf(x,0.f) + log1pf(expf(-fabsf(x))); }
__device__ inline float blo(unsigned u){ return __uint_as_float(u<<16); }
__device__ inline float bhi(unsigned u){ return __uint_as_float(u & 0xffff0000u); }
__device__ inline unsigned short f2bf(float f){
  unsigned u = __float_as_uint(f);
  return (unsigned short)((u + 0x7fffu + ((u>>16)&1u)) >> 16);
}
__device__ inline unsigned packbf(float a, float b){
  return (unsigned)f2bf(a) | ((unsigned)f2bf(b) << 16);
}

// ---- agent-coherent (MALL) access helpers ----
__device__ inline void stc_f(float* p, float v){
  asm volatile("global_store_dword %0, %1, off sc1" :: "v"(p), "v"(v) : "memory");
}
__device__ inline void stc_u(unsigned* p, unsigned v){
  asm volatile("global_store_dword %0, %1, off sc1" :: "v"(p), "v"(v) : "memory");
}
#define LDC4F(dst, addr) asm volatile("global_load_dwordx4 %0, %1, off sc1" : "=v"(dst) : "v"(addr) : "memory")
#define LDC4U(dst, addr) asm volatile("global_load_dwordx4 %0, %1, off sc1" : "=v"(dst) : "v"(addr) : "memory")
#define LDCF(dst, addr)  asm volatile("global_load_dword %0, %1, off sc1"  : "=v"(dst) : "v"(addr) : "memory")
#define WAITV do { asm volatile("s_waitcnt vmcnt(0)" ::: "memory"); __builtin_amdgcn_sched_barrier(0); } while(0)

#define AADD(p,v) __hip_atomic_fetch_add((p),(v),__ATOMIC_RELAXED,__HIP_MEMORY_SCOPE_AGENT)
#define ALD(p)    __hip_atomic_load((p),__ATOMIC_RELAXED,__HIP_MEMORY_SCOPE_AGENT)
#define AST(p,v)  __hip_atomic_store((p),(v),__ATOMIC_RELAXED,__HIP_MEMORY_SCOPE_AGENT)

__device__ inline float headact(int o, float s){
  if (o < 64)  return tanhf(s);
  if (o == 64) return softplusf(s);
  if (o == 65) return sigf(s);
  if (o == 66) return 1.f + softplusf(s);
  if (o < 131) return tanhf(s);
  if (o == 131) return softplusf(s);
  if (o < 196) return sigf(s);
  return tanhf(s);
}

__device__ inline void head_src(const KP& P, int o, const float** row, float* bias){
  if (o < 64)       { *row = P.rkW + o*Cv;        *bias = P.rkb[o]; }
  else if (o == 64) { *row = P.rsW;               *bias = P.rsb[0]; }
  else if (o == 65) { *row = P.rgW;               *bias = P.rgb[0]; }
  else if (o == 66) { *row = P.rgammaW;           *bias = P.rgammab[0]; }
  else if (o < 131) { *row = P.wkW + (o-67)*Cv;   *bias = P.wkb[o-67]; }
  else if (o == 131){ *row = P.wsW;               *bias = P.wsb[0]; }
  else if (o < 196) { *row = P.weW + (o-132)*Cv;  *bias = P.web[o-132]; }
  else              { *row = P.waW + (o-196)*Cv;  *bias = P.wab[o-196]; }
}

// hierarchical global barrier, split-phase, monotonic, watchdog'd
__device__ inline void gb_arrive(int* wsi, int b, int gstep){
  asm volatile("s_waitcnt vmcnt(0)" ::: "memory");
  __syncthreads();
  if (threadIdx.x == 0){
    int a = AADD(&wsi[GA_I(b)], 1);
    if (a == 8*gstep - 1) AADD(&wsi[ROOT_I], 1);
  }
}
__device__ inline void gb_wait(int* wsi, int b, int k, int gstep, unsigned long long t0){
  if (threadIdx.x == 0){
    unsigned sp = 0;
    if (k == 0){
      while (ALD(&wsi[ROOT_I]) < 32*gstep){
        __builtin_amdgcn_s_sleep(2);
        if (((++sp)&1023u)==0u && (__builtin_amdgcn_s_memrealtime()-t0) > 300000000ULL) break;
      }
      AST(&wsi[REL_I(b)], gstep);
    } else {
      while (ALD(&wsi[REL_I(b)]) < gstep){
        __builtin_amdgcn_s_sleep(2);
        if (((++sp)&1023u)==0u && (__builtin_amdgcn_s_memrealtime()-t0) > 300000000ULL) break;
      }
    }
  }
  __syncthreads();
}
// per-b 8-block barrier (plain)
__device__ inline void pb_bar(int* wsi, int b, int pbstep, unsigned long long t0){
  asm volatile("s_waitcnt vmcnt(0)" ::: "memory");
  __syncthreads();
  if (threadIdx.x == 0){
    AADD(&wsi[PBC_I(b)], 1);
    unsigned sp = 0;
    while (ALD(&wsi[PBC_I(b)]) < 8*pbstep){
      __builtin_amdgcn_s_sleep(2);
      if (((++sp)&1023u)==0u && (__builtin_amdgcn_s_memrealtime()-t0) > 300000000ULL) break;
    }
  }
  __syncthreads();
}

__global__ __launch_bounds__(NTHR) void ntm_kernel(KP P){
  __shared__ unsigned Wg[8][420];     // packed bf16 gate-weight rows (this block's 8 channels)
  __shared__ float gbias[8];
  __shared__ float memL[128][65];     // block's memory slice fp32, padded
  __shared__ unsigned hL[32][260];    // staged h(t-1), packed bf16 pairs, padded
  __shared__ float rvL[32][68];       // staged rv(t-1) fp32, padded
  __shared__ unsigned hdW[33][260];   // head-weight slice (rank k's ~33 rows), packed bf16
  __shared__ float hdB[33];
  __shared__ unsigned hbL[256];       // h(t) of own batch b, packed
  __shared__ float outWrow[576];
  __shared__ float outbj[1];
  __shared__ float gatebuf[32][9];
  __shared__ float knr[64], knw[64];
  __shared__ float scal[8];
  __shared__ float fwL[128], wwL[128];
  __shared__ float erL[64], adL[64];
  __shared__ float red[32][9];
  __shared__ float red2[4];
  __shared__ float rvpart[4][64];

  const int tid = threadIdx.x;
  const int bid = blockIdx.x;
  float* wsf = P.ws;
  int* wsi = (int*)P.ws;
  unsigned* hub = (unsigned*)P.ws + HUBASE;
  const int b = bid & 31;
  const int k = bid >> 5;            // group rank 0..7 (owns 128 mem rows + head slice)
  float* headsB = wsf + HEADBASE + b*264;
  const unsigned long long t0 = __builtin_amdgcn_s_memrealtime();

  // ---------------- startup ----------------
  for (int idx = tid; idx < 8*416; idx += NTHR){
    int rl = idx / 416, u = idx % 416;
    int r = (rl>>1)*Cv + 2*bid + (rl&1);
    float a, b2;
    if (u < 160){ a = P.Wih[r*320 + 2*u];      b2 = P.Wih[r*320 + 2*u + 1]; }
    else        { int q = 2*(u-160); a = P.Whh[r*512 + q]; b2 = P.Whh[r*512 + q + 1]; }
    Wg[rl][u] = packbf(a, b2);
  }
  if (tid < 8){
    int rl = tid; int r = (rl>>1)*Cv + 2*bid + (rl&1);
    gbias[rl] = P.bih[r] + P.bhh[r];
  }
  const int oBase = k*33;
  const int oCnt  = (k == 7) ? 29 : 33;
  for (int idx = tid; idx < oCnt*256; idx += NTHR){
    int oo = idx >> 8, m = idx & 255;
    const float* row; float bias;
    head_src(P, oBase + oo, &row, &bias);
    hdW[oo][m] = packbf(row[2*m], row[2*m+1]);
    if (m == 0) hdB[oo] = bias;
  }
  for (int q = tid; q < 576; q += NTHR) outWrow[q] = P.outW[bid*576 + q];
  if (tid == 0) outbj[0] = P.outb[bid];
  for (int idx = tid; idx < 128*65; idx += NTHR) ((float*)memL)[idx] = 0.f;
  __syncthreads();

  float c0 = 0.f, c1 = 0.f;             // LSTM cell state (tid<32)
  float er = 0.f, eg = 0.f, ew = 0.f;   // live across pb2
  int gs = 0, pbs = 0;

  for (int t = 0; t < Sv; ++t){
    // ===== S1: stage h(t-1)+rv(t-1); gate GEMM; h/c update; [GB1.arrive]; out-proj(t-1); [GB1.wait] =====
    {
      float4 r0, r1;
      const float* rs = wsf + RVBASE + ((t+1)&1)*2048 + tid*4;
      LDC4F(r0, rs);
      LDC4F(r1, rs + 1024);
      uint4 q0,q1,q2,q3,q4,q5,q6,q7;
      const unsigned* hs = hub + ((t+1)&1)*8192 + tid*4;
      LDC4U(q0, hs + 0*1024); LDC4U(q1, hs + 1*1024);
      LDC4U(q2, hs + 2*1024); LDC4U(q3, hs + 3*1024);
      LDC4U(q4, hs + 4*1024); LDC4U(q5, hs + 5*1024);
      LDC4U(q6, hs + 6*1024); LDC4U(q7, hs + 7*1024);
      WAITV;
      int rr = tid >> 4, rc = (tid & 15) * 4;
      *(float4*)&rvL[rr][rc] = r0;
      *(float4*)&rvL[16+rr][rc] = r1;
      int sr = tid >> 6, sc = (tid & 63) * 4;
      *(uint4*)&hL[ 0+sr][sc] = q0; *(uint4*)&hL[ 4+sr][sc] = q1;
      *(uint4*)&hL[ 8+sr][sc] = q2; *(uint4*)&hL[12+sr][sc] = q3;
      *(uint4*)&hL[16+sr][sc] = q4; *(uint4*)&hL[20+sr][sc] = q5;
      *(uint4*)&hL[24+sr][sc] = q6; *(uint4*)&hL[28+sr][sc] = q7;
    }
    __syncthreads();
    {
      const int bb = tid >> 3, rl = tid & 7;
      float acc = gbias[rl];
      const float* xb = P.x + ((size_t)bb*Sv + (size_t)t)*Iv;
      #pragma unroll 8
      for (int u = 0; u < 128; u += 2){
        uint2 w = *(const uint2*)&Wg[rl][u];
        float4 xv = *(const float4*)(xb + 2*u);
        acc += blo(w.x)*xv.x + bhi(w.x)*xv.y + blo(w.y)*xv.z + bhi(w.y)*xv.w;
      }
      #pragma unroll 8
      for (int u = 0; u < 32; u += 2){
        uint2 w = *(const uint2*)&Wg[rl][128+u];
        float4 xv = *(const float4*)&rvL[bb][2*u];
        acc += blo(w.x)*xv.x + bhi(w.x)*xv.y + blo(w.y)*xv.z + bhi(w.y)*xv.w;
      }
      #pragma unroll 8
      for (int u = 0; u < 256; u += 2){
        uint2 w = *(const uint2*)&Wg[rl][160+u];
        uint2 hp = *(const uint2*)&hL[bb][u];
        acc += blo(w.x)*blo(hp.x) + bhi(w.x)*bhi(hp.x)
             + blo(w.y)*blo(hp.y) + bhi(w.y)*bhi(hp.y);
      }
      gatebuf[bb][rl] = acc;
    }
    __syncthreads();
    if (tid < 32){
      float ig0=gatebuf[tid][0], ig1=gatebuf[tid][1];
      float fg0=gatebuf[tid][2], fg1=gatebuf[tid][3];
      float gg0=gatebuf[tid][4], gg1=gatebuf[tid][5];
      float og0=gatebuf[tid][6], og1=gatebuf[tid][7];
      c0 = sigf(fg0)*c0 + sigf(ig0)*tanhf(gg0);
      c1 = sigf(fg1)*c1 + sigf(ig1)*tanhf(gg1);
      float h0 = sigf(og0)*tanhf(c0);
      float h1 = sigf(og1)*tanhf(c1);
      stc_u(&hub[(t&1)*8192 + tid*256 + bid], packbf(h0, h1));
    }
    gb_arrive(wsi, b, ++gs);                       // h(t) in flight & drained
    if (t > 0){
      int bb2 = tid >> 3, kc = tid & 7;
      float p = 0.f;
      if (kc < 7){
        int j0 = kc*36;
        #pragma unroll
        for (int j = 0; j < 36; ++j){
          unsigned u = hL[bb2][j0+j];
          p += blo(u)*outWrow[2*(j0+j)] + bhi(u)*outWrow[2*(j0+j)+1];
        }
      } else {
        #pragma unroll
        for (int j = 252; j < 256; ++j){
          unsigned u = hL[bb2][j];
          p += blo(u)*outWrow[2*j] + bhi(u)*outWrow[2*j+1];
        }
        #pragma unroll 16
        for (int v = 0; v < 64; ++v) p += outWrow[512+v]*rvL[bb2][v];
      }
      red[bb2][kc] = p;
      __syncthreads();
      if (tid < 32){
        float s2 = outbj[0];
        #pragma unroll
        for (int k2 = 0; k2 < 8; ++k2) s2 += red[tid][k2];
        P.out[((size_t)tid*Sv + (t-1))*Ov + bid] = s2;
      }
    }
    gb_wait(wsi, b, k, gs, t0);

    // ===== S2: stage h(t)[b]; head linears (rank slice); zero next-step accumulators; pb1 =====
    if (tid < 64){
      uint4 hq;
      const unsigned* hs2 = hub + (t&1)*8192 + b*256 + tid*4;
      LDC4U(hq, hs2);
      WAITV;
      *(uint4*)&hbL[tid*4] = hq;
    }
    __syncthreads();
    {
      int oo = tid >> 3, kc = tid & 7;
      float p = 0.f;
      if (oo < oCnt){
        #pragma unroll
        for (int j = 0; j < 32; ++j){
          int m = kc + 8*j;
          unsigned w = hdW[oo][m], h = hbL[m];
          p += blo(w)*blo(h) + bhi(w)*bhi(h);
        }
      }
      __syncthreads();
      red[oo][kc] = p;
      __syncthreads();
      if (tid < 32 && tid < oCnt){
        float s2 = hdB[tid];
        #pragma unroll
        for (int k2 = 0; k2 < 8; ++k2) s2 += red[tid][k2];
        int o = oBase + tid;
        stc_f(&headsB[o], headact(o, s2));
      }
    }
    if (oCnt > 32){  // 33rd output (ranks 0..6)
      unsigned w = hdW[32][tid], h = hbL[tid];
      float p = blo(w)*blo(h) + bhi(w)*bhi(h);
      #pragma unroll
      for (int off = 32; off; off >>= 1) p += __shfl_xor(p, off);
      if ((tid & 63) == 0) red2[tid>>6] = p;
      __syncthreads();
      if (tid == 0){
        float s2 = hdB[32] + red2[0] + red2[1] + red2[2] + red2[3];
        int o = oBase + 32;
        stc_f(&headsB[o], headact(o, s2));
      }
    }
    if (k == 1){  // zero next-step accumulators (buffer (t+1)&1) — race-free, see analysis
      if (tid < 64) stc_f(&wsf[RVBASE + ((t+1)&1)*2048 + b*64 + tid], 0.f);
      if (tid < 8)  stc_f(&wsf[SUMBASE + ((t+1)&1)*256 + b*8 + tid], 0.f);
    }
    pb_bar(wsi, b, ++pbs, t0);

    // ===== S3: content addressing + per-b partial sums; pb2 =====
    {
      float kr = 0.f, kw = 0.f, s_r = 0.f, s_g = 0.f, s_gam = 0.f, s_sw = 0.f;
      if (tid < 64){
        LDCF(kr, headsB + tid);
        LDCF(kw, headsB + 67 + tid);
      }
      if (tid == 0){
        LDCF(s_r, headsB + 64);  LDCF(s_g, headsB + 65);
        LDCF(s_gam, headsB + 66); LDCF(s_sw, headsB + 131);
      }
      WAITV;
      if (tid < 64){
        float sr = kr*kr, sw2 = kw*kw;
        #pragma unroll
        for (int off = 32; off; off >>= 1){ sr += __shfl_xor(sr, off); sw2 += __shfl_xor(sw2, off); }
        knr[tid] = kr * (1.f/fmaxf(sqrtf(sr), 1e-12f));
        knw[tid] = kw * (1.f/fmaxf(sqrtf(sw2), 1e-12f));
        if (tid == 0){ scal[0]=s_r; scal[1]=s_g; scal[2]=s_gam; scal[3]=s_sw; }
      }
    }
    __syncthreads();
    er = 0.f; eg = 0.f; ew = 0.f;
    {
      float str_r = scal[0], gamma = scal[2], str_w = scal[3];
      if (tid < 128){
        float dr = 0.f, dw = 0.f, nn = 0.f;
        #pragma unroll 8
        for (int v = 0; v < 64; ++v){
          float m = memL[tid][v];
          dr += m*knr[v]; dw += m*knw[v]; nn += m*m;
        }
        float innm = 1.f/fmaxf(sqrtf(nn), 1e-12f);
        float tr = str_r*(dr*innm - 1.f);
        er = expf(tr);
        eg = expf(gamma*tr);
        ew = expf(str_w*(dw*innm - 1.f));
      }
      float s0 = er, s1 = eg, s2 = ew;
      #pragma unroll
      for (int off = 32; off; off >>= 1){
        s0 += __shfl_xor(s0, off); s1 += __shfl_xor(s1, off); s2 += __shfl_xor(s2, off);
      }
      if ((tid & 63) == 0 && tid < 128){
        int w2 = tid >> 6; red[w2][0] = s0; red[w2][1] = s1; red[w2][2] = s2;
      }
      __syncthreads();
      if (tid == 0){
        float* sb = wsf + SUMBASE + (t&1)*256 + b*8;
        atomicAdd(sb + 0, red[0][0] + red[1][0]);
        atomicAdd(sb + 1, red[0][1] + red[1][1]);
        atomicAdd(sb + 2, red[0][2] + red[1][2]);
      }
    }
    pb_bar(wsi, b, ++pbs, t0);

    // ===== S4: fw, read-vector add; [GB2.arrive]; memory update; [GB2.wait] =====
    {
      float Se = 0.f, Sg = 0.f, Sw = 0.f, erv = 0.f, adv = 0.f;
      const float* sb = wsf + SUMBASE + (t&1)*256 + b*8;
      if (tid == 0){ LDCF(Se, sb+0); LDCF(Sg, sb+1); LDCF(Sw, sb+2); }
      if (tid < 64){
        LDCF(erv, headsB + 132 + tid);
        LDCF(adv, headsB + 196 + tid);
      }
      WAITV;
      if (tid == 0){ scal[4]=Se; scal[5]=Sg; scal[6]=Sw; }
      if (tid < 64){ erL[tid] = erv; adL[tid] = adv; }
    }
    __syncthreads();
    {
      float Se = scal[4], Sg = scal[5], Sw = scal[6], gate_s = scal[1];
      if (tid < 128){
        fwL[tid] = gate_s*(eg/Sg) + (1.f - gate_s)*(er/Se);
        wwL[tid] = ew/Sw;
      }
    }
    __syncthreads();
    {
      int v = tid & 63, cc = tid >> 6;
      float p = 0.f;
      #pragma unroll 8
      for (int j = 0; j < 32; ++j){ int r = cc*32 + j; p += fwL[r]*memL[r][v]; }
      rvpart[cc][v] = p;
    }
    __syncthreads();
    if (tid < 64)
      atomicAdd(&wsf[RVBASE + (t&1)*2048 + b*64 + tid],
                rvpart[0][tid] + rvpart[1][tid] + rvpart[2][tid] + rvpart[3][tid]);
    gb_arrive(wsi, b, ++gs);                       // rv(t) adds drained
    #pragma unroll 4
    for (int e2 = 0; e2 < 32; ++e2){
      int flat = tid + e2*256;
      int r = flat >> 6, v2 = flat & 63;
      memL[r][v2] = memL[r][v2]*(1.f - wwL[r]*erL[v2]) + wwL[r]*adL[v2];
    }
    gb_wait(wsi, b, k, gs, t0);
  }

  // ===== epilogue: out-proj(S-1) =====
  {
    float4 r0, r1;
    const float* rs = wsf + RVBASE + ((Sv-1)&1)*2048 + tid*4;
    LDC4F(r0, rs);
    LDC4F(r1, rs + 1024);
    uint4 q0,q1,q2,q3,q4,q5,q6,q7;
    const unsigned* hs = hub + ((Sv-1)&1)*8192 + tid*4;
    LDC4U(q0, hs + 0*1024); LDC4U(q1, hs + 1*1024);
    LDC4U(q2, hs + 2*1024); LDC4U(q3, hs + 3*1024);
    LDC4U(q4, hs + 4*1024); LDC4U(q5, hs + 5*1024);
    LDC4U(q6, hs + 6*1024); LDC4U(q7, hs + 7*1024);
    WAITV;
    int rr = tid >> 4, rc = (tid & 15) * 4;
    *(float4*)&rvL[rr][rc] = r0;
    *(float4*)&rvL[16+rr][rc] = r1;
    int sr = tid >> 6, sc = (tid & 63) * 4;
    *(uint4*)&hL[ 0+sr][sc] = q0; *(uint4*)&hL[ 4+sr][sc] = q1;
    *(uint4*)&hL[ 8+sr][sc] = q2; *(uint4*)&hL[12+sr][sc] = q3;
    *(uint4*)&hL[16+sr][sc] = q4; *(uint4*)&hL[20+sr][sc] = q5;
    *(uint4*)&hL[24+sr][sc] = q6; *(uint4*)&hL[28+sr][sc] = q7;
  }
  __syncthreads();
  {
    int bb2 = tid >> 3, kc = tid & 7;
    float p = 0.f;
    if (kc < 7){
      int j0 = kc*36;
      #pragma unroll
      for (int j = 0; j < 36; ++j){
        unsigned u = hL[bb2][j0+j];
        p += blo(u)*outWrow[2*(j0+j)] + bhi(u)*outWrow[2*(j0+j)+1];
      }
    } else {
      #pragma unroll
      for (int j = 252; j < 256; ++j){
        unsigned u = hL[bb2][j];
        p += blo(u)*outWrow[2*j] + bhi(u)*outWrow[2*j+1];
      }
      #pragma unroll 16
      for (int v = 0; v < 64; ++v) p += outWrow[512+v]*rvL[bb2][v];
    }
    red[bb2][kc] = p;
    __syncthreads();
    if (tid < 32){
      float s2 = outbj[0];
      #pragma unroll
      for (int k2 = 0; k2 < 8; ++k2) s2 += red[tid][k2];
      P.out[((size_t)tid*Sv + (Sv-1))*Ov + bid] = s2;
    }
  }
  // ===== epilogue: final memory writeout =====
  for (int e2 = 0; e2 < 32; ++e2){
    int flat = tid + e2*256;
    int r = flat >> 6, v2 = flat & 63;
    P.memout[((size_t)b*Nv + (size_t)k*128 + r)*Vv + v2] = memL[r][v2];
  }
}

extern "C" void kernel_launch(void* const* d_in, const int* in_sizes, int n_in,
                              void* d_out, int out_size, void* d_ws, size_t ws_size,
                              hipStream_t stream) {
  (void)in_sizes; (void)n_in; (void)out_size; (void)ws_size;
  KP p;
  p.x       = (const float*)d_in[0];
  p.Wih     = (const float*)d_in[1];
  p.Whh     = (const float*)d_in[2];
  p.bih     = (const float*)d_in[3];
  p.bhh     = (const float*)d_in[4];
  p.rkW     = (const float*)d_in[5];  p.rkb     = (const float*)d_in[6];
  p.rsW     = (const float*)d_in[7];  p.rsb     = (const float*)d_in[8];
  p.rgW     = (const float*)d_in[9];  p.rgb     = (const float*)d_in[10];
  p.rgammaW = (const float*)d_in[13]; p.rgammab = (const float*)d_in[14];
  p.wkW     = (const float*)d_in[15]; p.wkb     = (const float*)d_in[16];
  p.wsW     = (const float*)d_in[17]; p.wsb     = (const float*)d_in[18];
  p.weW     = (const float*)d_in[19]; p.web     = (const float*)d_in[20];
  p.waW     = (const float*)d_in[21]; p.wab     = (const float*)d_in[22];
  p.outW    = (const float*)d_in[23]; p.outb    = (const float*)d_in[24];
  p.out     = (float*)d_out;
  p.memout  = (float*)d_out + (size_t)Bv*Sv*Ov;
  p.ws      = (float*)d_ws;

  hipMemsetAsync(d_ws, 0, ZERO_BYTES, stream);
  hipLaunchKernelGGL(ntm_kernel, dim3(NBLK), dim3(NTHR), 0, stream, p);
}

// Round 6
// 4942.091 us; speedup vs baseline: 3.8407x; 1.4276x over previous
//
#include <hip/hip_runtime.h>

#define Bv 32
#define Sv 256
#define Iv 256
#define Cv 512
#define Nv 1024
#define Vv 64
#define Ov 256
#define NBLK 256
#define NTHR 256

// ---- ws layout ----
// int region: 64B-spaced lines (8 ints apart)
#define CLAIM_I(x)   ((x)*8)
#define GAL_I(x,q)   (64 + ((x)*4+(q))*8)
#define XROOT_I(x)   (320 + (x)*8)
#define PB_I(x,b)    (384 + ((x)*4+(b))*8)
#define ZERO_BYTES   (640*4)
// data region (uint/float indices)
#define FBASE 1024
#define HBU(x,t1,bb)  (FBASE + (x)*2048 + (t1)*1024 + (bb)*256)        // 256 uints (512 f16 h)
#define RVPU(x,bb,k)  (FBASE + 16384 + (x)*1024 + (bb)*256 + (k)*32)  // 32 uints (64 f16 rv partial)
#define SUMPF(x,bb,k) (FBASE + 24576 + (x)*128 + (bb)*32 + (k)*4)     // 4 floats
#define HDSF(x,bb)    (FBASE + 25600 + ((x)*4+(bb))*260)              // 260 floats
// total = (1024 + 33920)*4 = 139,776 B  (<= 140,800 proven-available)

struct KP {
  const float *x, *Wih, *Whh, *bih, *bhh;
  const float *rkW, *rkb, *rsW, *rsb, *rgW, *rgb, *rgammaW, *rgammab;
  const float *wkW, *wkb, *wsW, *wsb, *weW, *web, *waW, *wab;
  const float *outW, *outb;
  float *out;
  float *memout;
  float *ws;
};

typedef _Float16 half2v __attribute__((ext_vector_type(2)));
union HU { unsigned u; half2v h; };

__device__ inline float sigf(float x){ return 1.f/(1.f+expf(-x)); }
__device__ inline float softplusf(float x){ return fmaxf(x,0.f) + log1pf(expf(-fabsf(x))); }
__device__ inline unsigned packh(float a, float b){
  HU z; z.h = half2v{(_Float16)a, (_Float16)b}; return z.u;
}
__device__ inline float h2lo(unsigned u){ HU z; z.u = u; return (float)z.h.x; }
__device__ inline float h2hi(unsigned u){ HU z; z.u = u; return (float)z.h.y; }
__device__ inline float dot2(unsigned w, unsigned a, float acc){
  HU wu, au; wu.u = w; au.u = a;
  return __builtin_amdgcn_fdot2(wu.h, au.h, acc, false);
}

// ---- L2-local (sc0) access helpers ----
__device__ inline void stg_f(float* p, float v){
  asm volatile("global_store_dword %0, %1, off sc0" :: "v"(p), "v"(v) : "memory");
}
__device__ inline void stg_u(unsigned* p, unsigned v){
  asm volatile("global_store_dword %0, %1, off sc0" :: "v"(p), "v"(v) : "memory");
}
#define LDG4U(dst, addr) asm volatile("global_load_dwordx4 %0, %1, off sc0" : "=v"(dst) : "v"(addr) : "memory")
#define LDG4F(dst, addr) asm volatile("global_load_dwordx4 %0, %1, off sc0" : "=v"(dst) : "v"(addr) : "memory")
#define LDGU(dst, addr)  asm volatile("global_load_dword %0, %1, off sc0"  : "=v"(dst) : "v"(addr) : "memory")
#define WAITV do { asm volatile("s_waitcnt vmcnt(0)" ::: "memory"); __builtin_amdgcn_sched_barrier(0); } while(0)

#define AADD(p,v) __hip_atomic_fetch_add((p),(v),__ATOMIC_RELAXED,__HIP_MEMORY_SCOPE_AGENT)
#define ALD(p)    __hip_atomic_load((p),__ATOMIC_RELAXED,__HIP_MEMORY_SCOPE_AGENT)

#define SPIN(cond_expr) do { unsigned sp = 0; \
  while (cond_expr){ __builtin_amdgcn_s_sleep(2); \
    if (((++sp)&1023u)==0u && (__builtin_amdgcn_s_memrealtime()-t0) > 300000000ULL) break; } } while(0)

__device__ inline float headact(int o, float s){
  if (o < 64)  return tanhf(s);
  if (o == 64) return softplusf(s);
  if (o == 65) return sigf(s);
  if (o == 66) return 1.f + softplusf(s);
  if (o < 131) return tanhf(s);
  if (o == 131) return softplusf(s);
  if (o < 196) return sigf(s);
  return tanhf(s);
}
__device__ inline void head_src(const KP& P, int o, const float** row, float* bias){
  if (o < 64)       { *row = P.rkW + o*Cv;        *bias = P.rkb[o]; }
  else if (o == 64) { *row = P.rsW;               *bias = P.rsb[0]; }
  else if (o == 65) { *row = P.rgW;               *bias = P.rgb[0]; }
  else if (o == 66) { *row = P.rgammaW;           *bias = P.rgammab[0]; }
  else if (o < 131) { *row = P.wkW + (o-67)*Cv;   *bias = P.wkb[o-67]; }
  else if (o == 131){ *row = P.wsW;               *bias = P.wsb[0]; }
  else if (o < 196) { *row = P.weW + (o-132)*Cv;  *bias = P.web[o-132]; }
  else              { *row = P.waW + (o-196)*Cv;  *bias = P.wab[o-196]; }
}

__global__ __launch_bounds__(NTHR) void ntm_kernel(KP P){
  __shared__ unsigned Wg[64][420];    // f16-pair gate-W rows (this block's 64 rows), 416 used
  __shared__ unsigned actL[4][420];   // f16-pair activations [x(128)|rv(32)|h(256)] per local batch
  __shared__ float memL[128][66];     // memory slice fp32 (batch bl_own, rows rk8*128..)
  __shared__ float gb[64][4];
  __shared__ float biasL[64];
  __shared__ float htmpf[16][5];
  __shared__ unsigned hOwnL[256];
  __shared__ float headsL[264];
  __shared__ float knr[64], knw[64];
  __shared__ float scal[8];
  __shared__ float fwL[128], wwL[128];
  __shared__ float red[32][9];
  __shared__ float red2[2][4];
  __shared__ float sumred[8][4];
  __shared__ float rvpartL[4][64];
  __shared__ float rvfin[64];
  __shared__ int sXcd, sRank;

  const int tid = threadIdx.x;
  float* wsf = P.ws;
  unsigned* wsu = (unsigned*)P.ws;
  int* wsi = (int*)P.ws;
  const unsigned long long t0 = __builtin_amdgcn_s_memrealtime();

  // ---- XCD discovery + rank claim ----
  if (tid == 0){
    unsigned xcc;
    asm volatile("s_getreg_b32 %0, hwreg(20, 0, 32)" : "=s"(xcc));  // HW_REG_XCC_ID
    int xc = (int)(xcc & 7u);
    int rk = AADD(&wsi[CLAIM_I(xc)], 1);
    sXcd = xc; sRank = rk & 31;
  }
  __syncthreads();
  const int xcd = sXcd, rank = sRank;
  const int bl_own = rank >> 3;      // local batch this block owns for mem/heads/out
  const int rk8 = rank & 7;          // rank within the batch-group
  const int bglob = xcd*4 + bl_own;  // global batch index
  const int obase = (rk8 < 4) ? rk8*33 : 132 + (rk8-4)*32;   // head-output slice

  // ---- startup: pack gate W (f16) + bias into LDS; zero memory ----
  for (int idx = tid; idx < 64*416; idx += NTHR){
    int rl = idx / 416, u = idx % 416;
    int gr = (rl>>4)*Cv + rank*16 + (rl&15);
    int c0 = 2*u;
    float a, b2;
    if (c0 < 320){ a = P.Wih[gr*320 + c0]; b2 = P.Wih[gr*320 + c0 + 1]; }
    else { int q = c0 - 320; a = P.Whh[gr*512 + q]; b2 = P.Whh[gr*512 + q + 1]; }
    Wg[rl][u] = packh(a, b2);
  }
  if (tid < 64){
    int gr = (tid>>4)*Cv + rank*16 + (tid&15);
    biasL[tid] = P.bih[gr] + P.bhh[gr];
  }
  for (int idx = tid; idx < 128*66; idx += NTHR) ((float*)memL)[idx] = 0.f;
  __syncthreads();

  float cS = 0.f;                      // LSTM cell state (tid<64: (j,bb))
  float er = 0.f, eg = 0.f, ew = 0.f;  // live S3->S4 (tid<128)
  int gs = 0, pbs = 0;

  for (int t = 0; t < Sv; ++t){
    // ===== S1: stage act (x, rv(t-1), h(t-1)); GEMM; c/h; h store; XB1; outproj(t-1) =====
    {
      int bb = tid>>6, part = tid&63;
      const float* xp = P.x + ((size_t)(xcd*4+bb)*Sv + (size_t)t)*Iv + part*4;
      float4 xv = *(const float4*)xp;
      actL[bb][part*2]   = packh(xv.x, xv.y);
      actL[bb][part*2+1] = packh(xv.z, xv.w);
      if (t > 0){
        uint4 hq;
        LDG4U(hq, wsu + HBU(xcd,(t+1)&1,bb) + part*4);
        unsigned q0=0,q1=0,q2=0,q3=0,q4=0,q5=0,q6=0,q7=0;
        int b2 = tid>>5, uix = tid&31;
        if (tid < 128){
          const unsigned* rb = wsu + RVPU(xcd,b2,0) + uix;
          LDGU(q0, rb+0*32); LDGU(q1, rb+1*32); LDGU(q2, rb+2*32); LDGU(q3, rb+3*32);
          LDGU(q4, rb+4*32); LDGU(q5, rb+5*32); LDGU(q6, rb+6*32); LDGU(q7, rb+7*32);
        }
        WAITV;
        *(uint4*)&actL[bb][160 + part*4] = hq;
        if (tid < 128){
          float lo = h2lo(q0)+h2lo(q1)+h2lo(q2)+h2lo(q3)+h2lo(q4)+h2lo(q5)+h2lo(q6)+h2lo(q7);
          float hi = h2hi(q0)+h2hi(q1)+h2hi(q2)+h2hi(q3)+h2hi(q4)+h2hi(q5)+h2hi(q6)+h2hi(q7);
          actL[b2][128+uix] = packh(lo, hi);
        }
      } else {
        for (int idx = tid; idx < 4*288; idx += NTHR){
          int bb2 = idx/288, u = 128 + idx%288;
          actL[bb2][u] = 0u;
        }
      }
    }
    __syncthreads();
    {  // gate GEMM: wave=gate g, lane: rr=l>>2 (16 rows), bb=l&3
      int g = tid>>6, l = tid&63, rr = l>>2, bb = l&3, row = g*16+rr;
      const unsigned* wr = &Wg[row][0];
      const unsigned* ar = &actL[bb][0];
      float a0 = biasL[row], a1 = 0.f, a2 = 0.f, a3 = 0.f;
      #pragma unroll 13
      for (int u = 0; u < 416; u += 8){
        uint4 w0 = *(const uint4*)(wr+u);
        uint4 v0 = *(const uint4*)(ar+u);
        uint4 w1 = *(const uint4*)(wr+u+4);
        uint4 v1 = *(const uint4*)(ar+u+4);
        a0 = dot2(w0.x, v0.x, a0); a1 = dot2(w0.y, v0.y, a1);
        a2 = dot2(w0.z, v0.z, a2); a3 = dot2(w0.w, v0.w, a3);
        a0 = dot2(w1.x, v1.x, a0); a1 = dot2(w1.y, v1.y, a1);
        a2 = dot2(w1.z, v1.z, a2); a3 = dot2(w1.w, v1.w, a3);
      }
      gb[row][bb] = (a0+a1)+(a2+a3);
    }
    __syncthreads();
    if (tid < 64){
      int j = tid>>2, bb = tid&3;
      float ig = gb[j][bb], fg = gb[16+j][bb], gg = gb[32+j][bb], og = gb[48+j][bb];
      cS = sigf(fg)*cS + sigf(ig)*tanhf(gg);
      htmpf[j][bb] = sigf(og)*tanhf(cS);
    }
    __syncthreads();
    if (tid < 32){
      int pr = tid>>2, bb = tid&3;
      stg_u(wsu + HBU(xcd,t&1,bb) + rank*8 + pr, packh(htmpf[2*pr][bb], htmpf[2*pr+1][bb]));
    }
    // XB1.arrive (32-wide)
    WAITV;
    __syncthreads();
    if (tid == 0){
      int a = AADD(&wsi[GAL_I(xcd, rank>>3)], 1);
      if (a == 8*(gs+1) - 1) AADD(&wsi[XROOT_I(xcd)], 1);
    }
    if (t > 0){  // out-proj(t-1), hidden under XB1
      int oo = tid>>3, kc = tid&7;
      int o = rk8*32 + oo;
      const float* wrow = P.outW + o*576 + kc*72;
      const unsigned* ab = &actL[bl_own][0];
      float p = 0.f;
      if (kc < 7){
        int u0 = 160 + kc*36;
        #pragma unroll 9
        for (int i = 0; i < 36; ++i){
          unsigned u = ab[u0+i];
          p += h2lo(u)*wrow[2*i] + h2hi(u)*wrow[2*i+1];
        }
      } else {
        #pragma unroll
        for (int i = 0; i < 4; ++i){
          unsigned u = ab[412+i];
          p += h2lo(u)*wrow[2*i] + h2hi(u)*wrow[2*i+1];
        }
        #pragma unroll 8
        for (int i = 0; i < 32; ++i){
          unsigned u = ab[128+i];
          p += h2lo(u)*wrow[8+2*i] + h2hi(u)*wrow[9+2*i];
        }
      }
      red[oo][kc] = p;
      __syncthreads();
      if (tid < 32){
        int o2 = rk8*32 + tid;
        float s = P.outb[o2];
        #pragma unroll
        for (int k2 = 0; k2 < 8; ++k2) s += red[tid][k2];
        P.out[((size_t)bglob*Sv + (t-1))*Ov + o2] = s;
      }
    }
    // XB1.wait
    if (tid == 0){ SPIN(ALD(&wsi[XROOT_I(xcd)]) < 4*(gs+1)); }
    __syncthreads();
    ++gs;

    // ===== S2: heads for own batch (rank slice of 260 outputs) =====
    if (tid < 64){
      uint4 hq;
      LDG4U(hq, wsu + HBU(xcd,t&1,bl_own) + tid*4);
      WAITV;
      *(uint4*)&hOwnL[tid*4] = hq;
    }
    __syncthreads();
    {
      int oo = tid>>3, kc = tid&7;
      int o = obase + oo;
      const float* row; float bias;
      head_src(P, o, &row, &bias);
      float p = 0.f;
      #pragma unroll 8
      for (int i = 0; i < 32; ++i){
        unsigned u = hOwnL[kc*32 + i];
        p += h2lo(u)*row[kc*64 + 2*i] + h2hi(u)*row[kc*64 + 2*i + 1];
      }
      red[oo][kc] = p;
    }
    __syncthreads();
    if (tid < 32){
      int o = obase + tid;
      const float* row; float bias;
      head_src(P, o, &row, &bias);
      float s = bias;
      #pragma unroll
      for (int k2 = 0; k2 < 8; ++k2) s += red[tid][k2];
      stg_f(wsf + HDSF(xcd,bl_own) + o, headact(o, s));
    }
    if (rk8 < 4 && tid < 64){  // 33rd output of low ranks
      int o = obase + 32;
      const float* row; float bias;
      head_src(P, o, &row, &bias);
      float p = 0.f;
      #pragma unroll
      for (int i = 0; i < 4; ++i){
        unsigned u = hOwnL[tid*4 + i];
        p += h2lo(u)*row[tid*8 + 2*i] + h2hi(u)*row[tid*8 + 2*i + 1];
      }
      #pragma unroll
      for (int off = 32; off; off >>= 1) p += __shfl_xor(p, off);
      if (tid == 0) stg_f(wsf + HDSF(xcd,bl_own) + o, headact(o, bias + p));
    }
    // xb2 (8-wide, per (xcd, bl_own))
    WAITV;
    __syncthreads();
    if (tid == 0){
      AADD(&wsi[PB_I(xcd,bl_own)], 1);
      SPIN(ALD(&wsi[PB_I(xcd,bl_own)]) < 8*(pbs+1));
    }
    __syncthreads();
    ++pbs;

    // ===== S3: content addressing + partial sums =====
    if (tid < 65){
      float4 hv;
      LDG4F(hv, wsf + HDSF(xcd,bl_own) + tid*4);
      WAITV;
      *(float4*)&headsL[tid*4] = hv;
    }
    __syncthreads();
    if (tid < 64){
      float kr = headsL[tid], kw = headsL[67+tid];
      float sr = kr*kr, sw2 = kw*kw;
      #pragma unroll
      for (int off = 32; off; off >>= 1){ sr += __shfl_xor(sr, off); sw2 += __shfl_xor(sw2, off); }
      knr[tid] = kr * (1.f/fmaxf(sqrtf(sr), 1e-12f));
      knw[tid] = kw * (1.f/fmaxf(sqrtf(sw2), 1e-12f));
    }
    __syncthreads();
    er = 0.f; eg = 0.f; ew = 0.f;
    {
      float str_r = headsL[64], gamma = headsL[66], str_w = headsL[131];
      if (tid < 128){
        float dr = 0.f, dw = 0.f, nn = 0.f;
        #pragma unroll 8
        for (int v = 0; v < 64; ++v){
          float m = memL[tid][v];
          dr += m*knr[v]; dw += m*knw[v]; nn += m*m;
        }
        float innm = 1.f/fmaxf(sqrtf(nn), 1e-12f);
        float tr = str_r*(dr*innm - 1.f);
        er = expf(tr);
        eg = expf(gamma*tr);
        ew = expf(str_w*(dw*innm - 1.f));
      }
      float s0 = er, s1 = eg, s2 = ew;
      #pragma unroll
      for (int off = 32; off; off >>= 1){
        s0 += __shfl_xor(s0, off); s1 += __shfl_xor(s1, off); s2 += __shfl_xor(s2, off);
      }
      if ((tid & 63) == 0 && tid < 128){
        int wv = tid>>6; red2[wv][0] = s0; red2[wv][1] = s1; red2[wv][2] = s2;
      }
      __syncthreads();
      if (tid == 0){
        float* sp = wsf + SUMPF(xcd,bl_own,rk8);
        stg_f(sp+0, red2[0][0]+red2[1][0]);
        stg_f(sp+1, red2[0][1]+red2[1][1]);
        stg_f(sp+2, red2[0][2]+red2[1][2]);
      }
    }
    // xb3 (8-wide)
    WAITV;
    __syncthreads();
    if (tid == 0){
      AADD(&wsi[PB_I(xcd,bl_own)], 1);
      SPIN(ALD(&wsi[PB_I(xcd,bl_own)]) < 8*(pbs+1));
    }
    __syncthreads();
    ++pbs;

    // ===== S4: fw/ww, rv partial, mem update; XB4 =====
    if (tid < 8){
      float4 sv;
      LDG4F(sv, wsf + SUMPF(xcd,bl_own,tid));
      WAITV;
      *(float4*)&sumred[tid][0] = sv;
    }
    __syncthreads();
    if (tid == 0){
      float Se=0.f, Sg=0.f, Sw=0.f;
      #pragma unroll
      for (int k2 = 0; k2 < 8; ++k2){ Se += sumred[k2][0]; Sg += sumred[k2][1]; Sw += sumred[k2][2]; }
      scal[4]=Se; scal[5]=Sg; scal[6]=Sw;
    }
    __syncthreads();
    if (tid < 128){
      float gate_s = headsL[65];
      fwL[tid] = gate_s*(eg/scal[5]) + (1.f - gate_s)*(er/scal[4]);
      wwL[tid] = ew/scal[6];
    }
    __syncthreads();
    {
      int v = tid & 63, cc = tid >> 6;
      float p = 0.f;
      #pragma unroll 8
      for (int j = 0; j < 32; ++j){ int r = cc*32 + j; p += fwL[r]*memL[r][v]; }
      rvpartL[cc][v] = p;
    }
    __syncthreads();
    if (tid < 64) rvfin[tid] = rvpartL[0][tid]+rvpartL[1][tid]+rvpartL[2][tid]+rvpartL[3][tid];
    __syncthreads();
    if (tid < 32)
      stg_u(wsu + RVPU(xcd,bl_own,rk8) + tid, packh(rvfin[2*tid], rvfin[2*tid+1]));
    // XB4.arrive (32-wide), mem update hidden, then wait
    WAITV;
    __syncthreads();
    if (tid == 0){
      int a = AADD(&wsi[GAL_I(xcd, rank>>3)], 1);
      if (a == 8*(gs+1) - 1) AADD(&wsi[XROOT_I(xcd)], 1);
    }
    #pragma unroll 4
    for (int e2 = 0; e2 < 32; ++e2){
      int flat = tid + e2*256;
      int r = flat >> 6, v2 = flat & 63;
      memL[r][v2] = memL[r][v2]*(1.f - wwL[r]*headsL[132+v2]) + wwL[r]*headsL[196+v2];
    }
    if (tid == 0){ SPIN(ALD(&wsi[XROOT_I(xcd)]) < 4*(gs+1)); }
    __syncthreads();
    ++gs;
  }

  // ===== epilogue: stage final h/rv, out-proj(S-1) =====
  {
    int bb = tid>>6, part = tid&63;
    uint4 hq;
    LDG4U(hq, wsu + HBU(xcd,(Sv-1)&1,bb) + part*4);
    unsigned q0=0,q1=0,q2=0,q3=0,q4=0,q5=0,q6=0,q7=0;
    int b2 = tid>>5, uix = tid&31;
    if (tid < 128){
      const unsigned* rb = wsu + RVPU(xcd,b2,0) + uix;
      LDGU(q0, rb+0*32); LDGU(q1, rb+1*32); LDGU(q2, rb+2*32); LDGU(q3, rb+3*32);
      LDGU(q4, rb+4*32); LDGU(q5, rb+5*32); LDGU(q6, rb+6*32); LDGU(q7, rb+7*32);
    }
    WAITV;
    *(uint4*)&actL[bb][160 + part*4] = hq;
    if (tid < 128){
      float lo = h2lo(q0)+h2lo(q1)+h2lo(q2)+h2lo(q3)+h2lo(q4)+h2lo(q5)+h2lo(q6)+h2lo(q7);
      float hi = h2hi(q0)+h2hi(q1)+h2hi(q2)+h2hi(q3)+h2hi(q4)+h2hi(q5)+h2hi(q6)+h2hi(q7);
      actL[b2][128+uix] = packh(lo, hi);
    }
  }
  __syncthreads();
  {
    int oo = tid>>3, kc = tid&7;
    int o = rk8*32 + oo;
    const float* wrow = P.outW + o*576 + kc*72;
    const unsigned* ab = &actL[bl_own][0];
    float p = 0.f;
    if (kc < 7){
      int u0 = 160 + kc*36;
      #pragma unroll 9
      for (int i = 0; i < 36; ++i){
        unsigned u = ab[u0+i];
        p += h2lo(u)*wrow[2*i] + h2hi(u)*wrow[2*i+1];
      }
    } else {
      #pragma unroll
      for (int i = 0; i < 4; ++i){
        unsigned u = ab[412+i];
        p += h2lo(u)*wrow[2*i] + h2hi(u)*wrow[2*i+1];
      }
      #pragma unroll 8
      for (int i = 0; i < 32; ++i){
        unsigned u = ab[128+i];
        p += h2lo(u)*wrow[8+2*i] + h2hi(u)*wrow[9+2*i];
      }
    }
    red[oo][kc] = p;
    __syncthreads();
    if (tid < 32){
      int o2 = rk8*32 + tid;
      float s = P.outb[o2];
      #pragma unroll
      for (int k2 = 0; k2 < 8; ++k2) s += red[tid][k2];
      P.out[((size_t)bglob*Sv + (Sv-1))*Ov + o2] = s;
    }
  }
  // ===== epilogue: final memory writeout =====
  for (int e2 = 0; e2 < 32; ++e2){
    int flat = tid + e2*256;
    int r = flat >> 6, v2 = flat & 63;
    P.memout[((size_t)bglob*Nv + (size_t)rk8*128 + r)*Vv + v2] = memL[r][v2];
  }
}

extern "C" void kernel_launch(void* const* d_in, const int* in_sizes, int n_in,
                              void* d_out, int out_size, void* d_ws, size_t ws_size,
                              hipStream_t stream) {
  (void)in_sizes; (void)n_in; (void)out_size; (void)ws_size;
  KP p;
  p.x       = (const float*)d_in[0];
  p.Wih     = (const float*)d_in[1];
  p.Whh     = (const float*)d_in[2];
  p.bih     = (const float*)d_in[3];
  p.bhh     = (const float*)d_in[4];
  p.rkW     = (const float*)d_in[5];  p.rkb     = (const float*)d_in[6];
  p.rsW     = (const float*)d_in[7];  p.rsb     = (const float*)d_in[8];
  p.rgW     = (const float*)d_in[9];  p.rgb     = (const float*)d_in[10];
  p.rgammaW = (const float*)d_in[13]; p.rgammab = (const float*)d_in[14];
  p.wkW     = (const float*)d_in[15]; p.wkb     = (const float*)d_in[16];
  p.wsW     = (const float*)d_in[17]; p.wsb     = (const float*)d_in[18];
  p.weW     = (const float*)d_in[19]; p.web     = (const float*)d_in[20];
  p.waW     = (const float*)d_in[21]; p.wab     = (const float*)d_in[22];
  p.outW    = (const float*)d_in[23]; p.outb    = (const float*)d_in[24];
  p.out     = (float*)d_out;
  p.memout  = (float*)d_out + (size_t)Bv*Sv*Ov;
  p.ws      = (float*)d_ws;

  hipMemsetAsync(d_ws, 0, ZERO_BYTES, stream);   // claim + barrier lines only
  hipLaunchKernelGGL(ntm_kernel, dim3(NBLK), dim3(NTHR), 0, stream, p);
}